// Round 1
// 1708.781 us; speedup vs baseline: 1.0994x; 1.0994x over previous
//
#include <hip/hip_runtime.h>

typedef _Float16 f16;
typedef _Float16 f16x8 __attribute__((ext_vector_type(8)));
typedef float f32x4 __attribute__((ext_vector_type(4)));

#define DEV static __device__ __forceinline__

constexpr int  NPATCH = 1024;          // 4 * 16 * 16
constexpr int  LLEN   = 196;           // 14*14
constexpr long NLROWS = (long)NPATCH * LLEN;  // 200704

// async global->LDS, 16B per lane; dest = wave-uniform base + lane*16
DEV void g2l16(const void* g, void* l) {
  __builtin_amdgcn_global_load_lds(
      (const __attribute__((address_space(1))) unsigned int*)g,
      (__attribute__((address_space(3))) unsigned int*)l, 16, 0, 0);
}

DEV unsigned pk2(float a, float b) {
  union { f16 h[2]; unsigned u; } z;
  z.h[0] = (f16)a; z.h[1] = (f16)b;
  return z.u;
}

// ---------------- k0: G = Wq^T Wk (f16), u = Wk^T bq (f32), Wv -> f16 ----------------
__global__ __launch_bounds__(256) void k0_prep(
    const float* __restrict__ Wq, const float* __restrict__ Wk,
    const float* __restrict__ Wv, const float* __restrict__ bq,
    f16* __restrict__ G16, f16* __restrict__ Wv16, float* __restrict__ u32) {
  int bx = blockIdx.x, t = threadIdx.x;
  if (bx < 256) {
    int c = bx;  // G row (uniform per block -> scalar loads of Wq)
    float acc = 0.f;
    for (int o = 0; o < 256; ++o) acc += Wq[o*256 + c] * Wk[o*256 + t];
    G16[c*256 + t] = (f16)acc;
  } else if (bx == 256) {
    float acc = 0.f;
    for (int o = 0; o < 256; ++o) acc += bq[o] * Wk[o*256 + t];
    u32[t] = acc;
  } else {
    for (int r = 0; r < 256; ++r) Wv16[r*256 + t] = (f16)Wv[r*256 + t];
  }
}

// ---------------- k1: resize(bilinear,half-pixel)+patchify+f16 pack -> dst[nm][256] ----
// LDS tile = packed f16 pairs, [pair pr][x] (pr = (c-cc0)/2). 28.8KB -> 5 blocks/CU.
// Phase 2: 16B/lane writes; ub partial per 64-ch chunk -> ub4[chunk][nm] (no atomics).
__global__ __launch_bounds__(256) void k1_pack(
    const float* __restrict__ src, int Hs, int Ws, float invS,
    f16* __restrict__ dst, float* __restrict__ ub4,
    const float* __restrict__ u32, int do_ub) {
  __shared__ unsigned tile[32 * 225];   // [pr][x], stride 225 -> conflict-free both phases
  __shared__ float us[64];
  int bx = blockIdx.x;
  int cc0 = (bx & 3) * 64;
  int bi = bx >> 2;
  int i  = bi % 14; bi /= 14;
  int py = bi & 15; int b = bi >> 4;
  int y = py*14 + i;
  int t = threadIdx.x;
  if (t < 64) us[t] = u32[cc0 + t];

  if (invS == 1.0f) {
    // pure pack path (x input): float4 loads along x, 2 channel planes per thread
    int xh = t & 7, pr = t >> 3;                    // pr 0..31
    const float* b0 = src + ((long)(b*256 + cc0 + 2*pr)) * 50176 + y*224;
    const float* b1 = b0 + 50176;
#pragma unroll
    for (int it = 0; it < 7; ++it) {
      int x0 = (it*8 + xh) * 4;
      float4 va = *(const float4*)(b0 + x0);
      float4 vb = *(const float4*)(b1 + x0);
      tile[pr*225 + x0 + 0] = pk2(va.x, vb.x);
      tile[pr*225 + x0 + 1] = pk2(va.y, vb.y);
      tile[pr*225 + x0 + 2] = pk2(va.z, vb.z);
      tile[pr*225 + x0 + 3] = pk2(va.w, vb.w);
    }
  } else {
    float fy  = (y + 0.5f) * invS - 0.5f;
    float y0f = floorf(fy);
    float wy1 = fy - y0f, wy0 = 1.f - wy1;
    int y0 = (int)y0f, y1 = (int)y0f + 1;
    y0 = min(max(y0, 0), Hs-1); y1 = min(max(y1, 0), Hs-1);
    long plane = (long)Hs * Ws;
    int xl = t & 63, c4 = t >> 6;
    for (int xp = 0; xp < 4; ++xp) {
      int x = xp*64 + xl;
      if (x < 224) {
        float fx  = (x + 0.5f) * invS - 0.5f;
        float x0f = floorf(fx);
        float wx1 = fx - x0f, wx0 = 1.f - wx1;
        int x0 = (int)x0f, x1 = (int)x0f + 1;
        x0 = min(max(x0, 0), Ws-1); x1 = min(max(x1, 0), Ws-1);
        int o00 = y0*Ws + x0, o01 = y0*Ws + x1;
        int o10 = y1*Ws + x0, o11 = y1*Ws + x1;
#pragma unroll
        for (int pp = 0; pp < 8; ++pp) {
          int pr = c4*8 + pp;
          const float* base0 = src + ((long)(b*256 + cc0 + 2*pr)) * plane;
          const float* base1 = base0 + plane;
          float va = wy0*(wx0*base0[o00] + wx1*base0[o01])
                   + wy1*(wx0*base0[o10] + wx1*base0[o11]);
          float vb = wy0*(wx0*base1[o00] + wx1*base1[o01])
                   + wy1*(wx0*base1[o10] + wx1*base1[o11]);
          tile[pr*225 + x] = pk2(va, vb);
        }
      }
    }
  }
  __syncthreads();
  // phase 2: lane q covers pairs q*4..q*4+3 (channels q*8..q*8+7) of row x
  int q = t & 7, xg = t >> 3;
  float4 u0, u1;
  if (do_ub) {
    u0 = *(const float4*)(us + q*8);
    u1 = *(const float4*)(us + q*8 + 4);
  }
  for (int xo = 0; xo < 7; ++xo) {
    int x = xo*32 + xg;
    unsigned p0 = tile[(q*4+0)*225 + x];
    unsigned p1 = tile[(q*4+1)*225 + x];
    unsigned p2 = tile[(q*4+2)*225 + x];
    unsigned p3 = tile[(q*4+3)*225 + x];
    int px = x / 14, j = x % 14;
    int m = i*14 + j;
    long nm = (long)(b*256 + py*16 + px) * 196 + m;
    uint4 w; w.x = p0; w.y = p1; w.z = p2; w.w = p3;
    *reinterpret_cast<uint4*>(dst + nm*256 + cc0 + q*8) = w;
    if (do_ub) {
      union { unsigned u; f16 h[2]; } c0, c1, c2, c3;
      c0.u = p0; c1.u = p1; c2.u = p2; c3.u = p3;
      float part = u0.x*(float)c0.h[0] + u0.y*(float)c0.h[1]
                 + u0.z*(float)c1.h[0] + u0.w*(float)c1.h[1]
                 + u1.x*(float)c2.h[0] + u1.y*(float)c2.h[1]
                 + u1.z*(float)c3.h[0] + u1.w*(float)c3.h[1];
      part += __shfl_xor(part, 1);
      part += __shfl_xor(part, 2);
      part += __shfl_xor(part, 4);
      if (q == 0) ub4[(long)(bx & 3) * NLROWS + nm] = part;
    }
  }
}

// ---------------- k2: [Kt | V] = SPT * [G; Wv]^T. BM=64 nm-rows, BN=512, col-split waves ----------
// KtT[nm][256] (bt-layout for k3), V transposed via LDS -> VT2[n][c][224] (bt-layout for k4)
__global__ __launch_bounds__(256) void k2_kv(
    const f16* __restrict__ SPT, const f16* __restrict__ G16,
    const f16* __restrict__ Wv16, f16* __restrict__ KtT, f16* __restrict__ VT2) {
  __shared__ __align__(16) char ldsA[64 * 80];    // [row][32 f16 -> 80B padded]
  __shared__ __align__(16) char ldsB[512 * 80];   // reused as [64][258] f16 for V transpose
  int tid = threadIdx.x;
  int lane = tid & 63, wv = tid >> 6;
  long nm0 = (long)blockIdx.x * 64;
  f32x4 zero = {0.f, 0.f, 0.f, 0.f};
  f32x4 acc[4][8];
#pragma unroll
  for (int a = 0; a < 4; ++a)
#pragma unroll
    for (int bb = 0; bb < 8; ++bb) acc[a][bb] = zero;
  int col0 = wv * 128;
  int r15 = lane & 15, quad = lane >> 4;
  for (int k0 = 0; k0 < 256; k0 += 32) {
    __syncthreads();
#pragma unroll
    for (int call = 0; call < 2; ++call) {       // A: 320 slots
      int slot = call*256 + tid;
      if (slot < 320) {
        int row = slot / 5, part = slot % 5;
        int pp_ = part < 4 ? part : 0;           // slot 5 = pad, dup row start
        g2l16(SPT + ((nm0 + row)*256 + k0 + pp_*8), ldsA + slot*16);
      }
    }
#pragma unroll
    for (int call = 0; call < 10; ++call) {      // B: 2560 slots
      int slot = call*256 + tid;
      int row = slot / 5, part = slot % 5;
      int pp_ = part < 4 ? part : 0;
      const f16* g = (row < 256) ? (G16 + (row*256 + k0 + pp_*8))
                                 : (Wv16 + ((row - 256)*256 + k0 + pp_*8));
      g2l16(g, ldsB + slot*16);
    }
    __syncthreads();
    f16x8 af[4];
#pragma unroll
    for (int rt = 0; rt < 4; ++rt)
      af[rt] = *(const f16x8*)(ldsA + (rt*16 + r15)*80 + quad*16);
#pragma unroll
    for (int tc = 0; tc < 8; ++tc) {
      f16x8 bf = *(const f16x8*)(ldsB + (col0 + tc*16 + r15)*80 + quad*16);
#pragma unroll
      for (int rt = 0; rt < 4; ++rt)
        acc[rt][tc] = __builtin_amdgcn_mfma_f32_16x16x32_f16(af[rt], bf, acc[rt][tc], 0, 0, 0);
    }
  }
  __syncthreads();                // last MFMA ldsB reads done before reuse
  f16* ldsV = (f16*)ldsB;        // [64][258] (+2 pad -> bank-conflict-free transpose)
  if (wv >= 2) {                 // waves 2,3 hold V columns: stage to LDS
#pragma unroll
    for (int rt = 0; rt < 4; ++rt)
#pragma unroll
      for (int tc = 0; tc < 8; ++tc) {
        int o = col0 - 256 + tc*16 + r15;
#pragma unroll
        for (int reg = 0; reg < 4; ++reg) {
          int row = rt*16 + quad*4 + reg;
          ldsV[row*258 + o] = (f16)acc[rt][tc][reg];
        }
      }
  } else {                       // waves 0,1: K-tilde, already coalesced
#pragma unroll
    for (int rt = 0; rt < 4; ++rt)
#pragma unroll
      for (int tc = 0; tc < 8; ++tc) {
        int colc = col0 + tc*16 + r15;
#pragma unroll
        for (int reg = 0; reg < 4; ++reg) {
          long row = nm0 + rt*16 + quad*4 + reg;
          KtT[row*256 + colc] = (f16)acc[rt][tc][reg];
        }
      }
  }
  __syncthreads();
  {                              // transpose-write V: contiguous along m
    int row = tid & 63;
    long nm = nm0 + row;
    int n = (int)(nm / 196), m = (int)(nm % 196);
    long vbase = ((long)n * 256) * 224 + m;
    int o0 = (tid >> 6) * 64;
    for (int it = 0; it < 64; ++it) {
      int o = o0 + it;
      VT2[vbase + (long)o * 224] = ldsV[row*258 + o];
    }
  }
}

// ---------------- k3: S = XT . Kt^T per patch (+ub), row softmax -> P f16 [nl][224] ------------
__global__ __launch_bounds__(256) void k3_s(
    const f16* __restrict__ XT, const f16* __restrict__ KtT,
    const float* __restrict__ ub, f16* __restrict__ Pout) {
  __shared__ __align__(16) char ldsA[64 * 144];   // [l-row][64 f16 -> 144B padded]
  __shared__ __align__(16) char ldsB[208 * 144];  // [m-row][64 f16]
  __shared__ float ubs[208];
  int tid = threadIdx.x;
  int lane = tid & 63, wv = tid >> 6;
  int bx = blockIdx.x;
  // XCD swizzle: 4 blocks sharing KtT[n] slice land 8 apart -> same XCD, adjacent in time
  int n  = ((bx >> 5) << 3) | (bx & 7);
  int l0 = ((bx >> 3) & 3) * 64;
  long base = (long)n * 196;
  for (int s = tid; s < 208; s += 256) {
    float v = 0.f;
    if (s < 196) {
      long o = base + s;
      v = ub[o] + ub[NLROWS + o] + ub[2*NLROWS + o] + ub[3*NLROWS + o];
    }
    ubs[s] = v;
  }
  f32x4 zero = {0.f, 0.f, 0.f, 0.f};
  f32x4 acc[13];
#pragma unroll
  for (int t = 0; t < 13; ++t) acc[t] = zero;
  int r15 = lane & 15, quad = lane >> 4;
  for (int k0 = 0; k0 < 256; k0 += 64) {
    __syncthreads();
#pragma unroll
    for (int call = 0; call < 3; ++call) {        // A: 576 slots (9 per row)
      int slot = call*256 + tid;
      if (slot < 576) {
        int row = slot / 9, part = slot % 9;
        int pp_ = part < 8 ? part : 0;
        int l = l0 + row; l = l > 195 ? 195 : l;  // clamp ghost rows
        g2l16(XT + ((base + l)*256 + k0 + pp_*8), ldsA + slot*16);
      }
    }
#pragma unroll
    for (int call = 0; call < 8; ++call) {        // B: 1872 slots
      int slot = call*256 + tid;
      if (slot < 1872) {
        int row = slot / 9, part = slot % 9;
        int pp_ = part < 8 ? part : 0;
        int m = row > 195 ? 195 : row;
        g2l16(KtT + ((base + m)*256 + k0 + pp_*8), ldsB + slot*16);
      }
    }
    __syncthreads();
#pragma unroll
    for (int ks = 0; ks < 2; ++ks) {
      f16x8 af = *(const f16x8*)(ldsA + (wv*16 + r15)*144 + (ks*4 + quad)*16);
#pragma unroll
      for (int t = 0; t < 13; ++t) {
        f16x8 bf = *(const f16x8*)(ldsB + (t*16 + r15)*144 + (ks*4 + quad)*16);
        acc[t] = __builtin_amdgcn_mfma_f32_16x16x32_f16(af, bf, acc[t], 0, 0, 0);
      }
    }
  }
  // softmax over m (cols). C-layout: col = lane&15 + 16*t, row = quad*4+reg (+16*wv +l0)
  float mx[4] = {-1e30f, -1e30f, -1e30f, -1e30f};
#pragma unroll
  for (int t = 0; t < 13; ++t) {
    int colb = t*16 + r15;
    float ubv = ubs[colb];
    bool valid = colb < 196;
#pragma unroll
    for (int reg = 0; reg < 4; ++reg) {
      float v = acc[t][reg] + ubv;
      acc[t][reg] = v;
      if (valid) mx[reg] = fmaxf(mx[reg], v);
    }
  }
#pragma unroll
  for (int reg = 0; reg < 4; ++reg) {
    float m = mx[reg];
    m = fmaxf(m, __shfl_xor(m, 1));
    m = fmaxf(m, __shfl_xor(m, 2));
    m = fmaxf(m, __shfl_xor(m, 4));
    m = fmaxf(m, __shfl_xor(m, 8));
    mx[reg] = m;
  }
  float sum[4] = {0.f, 0.f, 0.f, 0.f};
#pragma unroll
  for (int t = 0; t < 13; ++t) {
    int colb = t*16 + r15;
    bool valid = colb < 196;
#pragma unroll
    for (int reg = 0; reg < 4; ++reg) {
      float p = valid ? __expf(acc[t][reg] - mx[reg]) : 0.f;
      acc[t][reg] = p;
      sum[reg] += p;
    }
  }
#pragma unroll
  for (int reg = 0; reg < 4; ++reg) {
    float s = sum[reg];
    s += __shfl_xor(s, 1);
    s += __shfl_xor(s, 2);
    s += __shfl_xor(s, 4);
    s += __shfl_xor(s, 8);
    sum[reg] = 1.0f / s;
  }
#pragma unroll
  for (int reg = 0; reg < 4; ++reg) {
    int l = l0 + wv*16 + quad*4 + reg;
    if (l < 196) {
      long prow = (base + l) * 224;
#pragma unroll
      for (int t = 0; t < 13; ++t)
        Pout[prow + t*16 + r15] = (f16)(acc[t][reg] * sum[reg]);
      Pout[prow + 208 + r15] = (f16)0.f;    // zero pad m in [208,224)
    }
  }
}

// ---------------- k4: O = P . V^T -> Obuf f16 [n][l][c] (coalesced; mode1 = +=) ---------------
// 2-phase double-buffered: stage(next) issued before compute(cur); one barrier per m-step.
__global__ __launch_bounds__(256) void k4_o(
    const f16* __restrict__ Pbuf, const f16* __restrict__ VT2,
    f16* __restrict__ Obuf, int mode) {
  __shared__ __align__(16) char ldsA[2][64 * 80];    // P tile [l][32 f16]
  __shared__ __align__(16) char ldsB[2][256 * 80];   // V tile [c][32 f16]
  int tid = threadIdx.x;
  int lane = tid & 63, wv = tid >> 6;
  int bx = blockIdx.x;
  int n  = ((bx >> 5) << 3) | (bx & 7);           // XCD swizzle (VT2[n] slice reuse)
  int l0 = ((bx >> 3) & 3) * 64;
  f32x4 zero = {0.f, 0.f, 0.f, 0.f};
  f32x4 acc[16];
#pragma unroll
  for (int t = 0; t < 16; ++t) acc[t] = zero;
  int r15 = lane & 15, quad = lane >> 4;

  auto stage = [&](int buf, int m0) {
#pragma unroll
    for (int call = 0; call < 2; ++call) {        // A: 320 slots
      int slot = call*256 + tid;
      if (slot < 320) {
        int row = slot / 5, part = slot % 5;
        int pp_ = part < 4 ? part : 0;
        long nl = (long)n*196 + l0 + row;
        if (nl > NLROWS - 1) nl = NLROWS - 1;     // ghost rows (discarded later)
        g2l16(Pbuf + (nl*224 + m0 + pp_*8), ldsA[buf] + slot*16);
      }
    }
#pragma unroll
    for (int call = 0; call < 5; ++call) {        // B: 1280 slots
      int slot = call*256 + tid;
      int row = slot / 5, part = slot % 5;
      int pp_ = part < 4 ? part : 0;
      g2l16(VT2 + (((long)(n*256 + row))*224 + m0 + pp_*8), ldsB[buf] + slot*16);
    }
  };

  stage(0, 0);
  __syncthreads();                                 // buf0 resident
  for (int it = 0; it < 7; ++it) {
    int cur = it & 1;
    if (it < 6) stage(cur ^ 1, 32*(it+1));         // prefetch overlaps compute below
    f16x8 af = *(const f16x8*)(ldsA[cur] + (wv*16 + r15)*80 + quad*16);
#pragma unroll
    for (int t = 0; t < 16; ++t) {
      f16x8 bf = *(const f16x8*)(ldsB[cur] + (t*16 + r15)*80 + quad*16);
      acc[t] = __builtin_amdgcn_mfma_f32_16x16x32_f16(af, bf, acc[t], 0, 0, 0);
    }
    __syncthreads();   // drains prefetch (vmcnt) + ds_reads (lgkm); next iter overwrites cur
  }
#pragma unroll
  for (int reg = 0; reg < 4; ++reg) {
    int l = l0 + wv*16 + quad*4 + reg;
    if (l < 196) {
      long orow = ((long)n*196 + l) * 256;
#pragma unroll
      for (int t = 0; t < 16; ++t) {
        int c = t*16 + r15;
        float v = acc[t][reg];
        if (mode == 0) Obuf[orow + c] = (f16)v;
        else           Obuf[orow + c] = (f16)(v + (float)Obuf[orow + c]);
      }
    }
  }
}

// ---------------- k5: unpatchify Obuf[n][l][c] -> out[b][c][yy][xx] + 2*bv -------------------
__global__ __launch_bounds__(256) void k5_unpatch(
    const f16* __restrict__ Obuf, const float* __restrict__ bv,
    float* __restrict__ out) {
  __shared__ float lds[64 * 225];   // [c_local][xx], stride 225 -> conflict-free both sides
  int bx = blockIdx.x;
  int cc = (bx & 3) * 64;  bx >>= 2;
  int i  = bx % 14; bx /= 14;
  int py = bx & 15; int b = bx >> 4;
  int t = threadIdx.x;
  int cl = t & 63, pg = t >> 6;
  for (int it = 0; it < 56; ++it) {
    int pr = it*4 + pg;            // (px,j) pair index, 0..223
    int px = pr / 14, j = pr % 14;
    int n = b*256 + py*16 + px;
    float v = (float)Obuf[((long)n*196 + i*14 + j)*256 + cc + cl];
    lds[cl*225 + px*14 + j] = v;
  }
  __syncthreads();
  int yy = py*14 + i;
  for (int c = 0; c < 64; ++c) {
    float bb = 2.0f * bv[cc + c];
    if (t < 224)
      out[(((long)(b*256 + cc + c))*224 + yy)*224 + t] = lds[c*225 + t] + bb;
  }
}

extern "C" void kernel_launch(void* const* d_in, const int* in_sizes, int n_in,
                              void* d_out, int out_size, void* d_ws, size_t ws_size,
                              hipStream_t stream) {
  (void)in_sizes; (void)n_in; (void)out_size; (void)ws_size;
  const float* x     = (const float*)d_in[0];
  const float* skip0 = (const float*)d_in[1];
  const float* skip1 = (const float*)d_in[2];
  const float* Wq    = (const float*)d_in[3];
  const float* bq    = (const float*)d_in[4];
  const float* Wk    = (const float*)d_in[5];
  // d_in[6] = bk: algebraically drops out of softmax (row-constant)
  const float* Wv    = (const float*)d_in[7];
  const float* bv    = (const float*)d_in[8];
  float* out = (float*)d_out;

  char* ws = (char*)d_ws;
  size_t off = 0;
  auto alloc = [&](size_t bytes) {
    char* p = ws + off;
    off += (bytes + 255) & ~(size_t)255;
    return p;
  };
  f16*   XT   = (f16*)  alloc((size_t)NLROWS * 256 * 2);   // x packed, f16 [nl][c]
  f16*   SPT  = (f16*)  alloc((size_t)NLROWS * 256 * 2);   // skip packed; region reused as P
  f16*   KtT  = (f16*)  alloc((size_t)NLROWS * 256 * 2);   // Ktilde [nm][c]
  f16*   VT2  = (f16*)  alloc((size_t)NPATCH * 256 * 224 * 2); // V [n][c][m(224)]
  f16*   Obuf = (f16*)  alloc((size_t)NLROWS * 256 * 2);   // O accum f16 [n][l][c]
  float* ub   = (float*)alloc((size_t)NLROWS * 4 * 4);     // 4 chunk-partials [4][nm]
  f16*   G16  = (f16*)  alloc(256 * 256 * 2);
  f16*   Wv16 = (f16*)  alloc(256 * 256 * 2);
  float* u32  = (float*)alloc(256 * 4);
  f16*   P    = SPT;   // P[nl][224] (89.9 MB) fits in SPT region (102.8 MB); SPT dead by k3

  k0_prep<<<258, 256, 0, stream>>>(Wq, Wk, Wv, bq, G16, Wv16, u32);
  k1_pack<<<3584, 256, 0, stream>>>(x, 224, 224, 1.0f, XT, nullptr, u32, 0);

  const float* skips[2] = {skip0, skip1};
  int   hs[2]   = {112, 56};
  float invs[2] = {0.5f, 0.25f};
  for (int s = 0; s < 2; ++s) {
    k1_pack<<<3584, 256, 0, stream>>>(skips[s], hs[s], hs[s], invs[s], SPT, ub, u32, 1);
    k2_kv<<<3136, 256, 0, stream>>>(SPT, G16, Wv16, KtT, VT2);
    k3_s <<<4096, 256, 0, stream>>>(XT, KtT, ub, P);
    k4_o <<<4096, 256, 0, stream>>>(P, VT2, Obuf, s);
  }
  k5_unpatch<<<3584, 256, 0, stream>>>(Obuf, bv, out);
}

// Round 2
// 1556.085 us; speedup vs baseline: 1.2073x; 1.0981x over previous
//
#include <hip/hip_runtime.h>

typedef _Float16 f16;
typedef _Float16 f16x8 __attribute__((ext_vector_type(8)));
typedef float f32x4 __attribute__((ext_vector_type(4)));

#define DEV static __device__ __forceinline__

constexpr int  NPATCH = 1024;          // 4 * 16 * 16
constexpr int  LLEN   = 196;           // 14*14
constexpr long NLROWS = (long)NPATCH * LLEN;  // 200704

// async global->LDS, 16B per lane; dest = wave-uniform base + lane*16
DEV void g2l16(const void* g, void* l) {
  __builtin_amdgcn_global_load_lds(
      (const __attribute__((address_space(1))) unsigned int*)g,
      (__attribute__((address_space(3))) unsigned int*)l, 16, 0, 0);
}

DEV unsigned pk2(float a, float b) {
  union { f16 h[2]; unsigned u; } z;
  z.h[0] = (f16)a; z.h[1] = (f16)b;
  return z.u;
}

// ---------------- k0: G = Wq^T Wk (f16), u = Wk^T bq (f32), Wv -> f16 ----------------
__global__ __launch_bounds__(256) void k0_prep(
    const float* __restrict__ Wq, const float* __restrict__ Wk,
    const float* __restrict__ Wv, const float* __restrict__ bq,
    f16* __restrict__ G16, f16* __restrict__ Wv16, float* __restrict__ u32) {
  int bx = blockIdx.x, t = threadIdx.x;
  if (bx < 256) {
    int c = bx;  // G row (uniform per block -> scalar loads of Wq)
    float acc = 0.f;
    for (int o = 0; o < 256; ++o) acc += Wq[o*256 + c] * Wk[o*256 + t];
    G16[c*256 + t] = (f16)acc;
  } else if (bx == 256) {
    float acc = 0.f;
    for (int o = 0; o < 256; ++o) acc += bq[o] * Wk[o*256 + t];
    u32[t] = acc;
  } else {
    for (int r = 0; r < 256; ++r) Wv16[r*256 + t] = (f16)Wv[r*256 + t];
  }
}

// ---------------- k1: resize(bilinear,half-pixel)+patchify+f16 pack -> dst[nm][256] ----
// LDS tile = packed f16 pairs, [pair pr][x] (pr = (c-cc0)/2). 28.8KB -> 5 blocks/CU.
// Phase 2: 16B/lane writes; ub partial per 64-ch chunk -> ub4[chunk][nm] (no atomics).
__global__ __launch_bounds__(256) void k1_pack(
    const float* __restrict__ src, int Hs, int Ws, float invS,
    f16* __restrict__ dst, float* __restrict__ ub4,
    const float* __restrict__ u32, int do_ub) {
  __shared__ unsigned tile[32 * 225];   // [pr][x], stride 225 -> conflict-free both phases
  __shared__ float us[64];
  int bx = blockIdx.x;
  int cc0 = (bx & 3) * 64;
  int bi = bx >> 2;
  int i  = bi % 14; bi /= 14;
  int py = bi & 15; int b = bi >> 4;
  int y = py*14 + i;
  int t = threadIdx.x;
  if (t < 64) us[t] = u32[cc0 + t];

  if (invS == 1.0f) {
    // pure pack path (x input): float4 loads along x, 2 channel planes per thread
    int xh = t & 7, pr = t >> 3;                    // pr 0..31
    const float* b0 = src + ((long)(b*256 + cc0 + 2*pr)) * 50176 + y*224;
    const float* b1 = b0 + 50176;
#pragma unroll
    for (int it = 0; it < 7; ++it) {
      int x0 = (it*8 + xh) * 4;
      float4 va = *(const float4*)(b0 + x0);
      float4 vb = *(const float4*)(b1 + x0);
      tile[pr*225 + x0 + 0] = pk2(va.x, vb.x);
      tile[pr*225 + x0 + 1] = pk2(va.y, vb.y);
      tile[pr*225 + x0 + 2] = pk2(va.z, vb.z);
      tile[pr*225 + x0 + 3] = pk2(va.w, vb.w);
    }
  } else {
    float fy  = (y + 0.5f) * invS - 0.5f;
    float y0f = floorf(fy);
    float wy1 = fy - y0f, wy0 = 1.f - wy1;
    int y0 = (int)y0f, y1 = (int)y0f + 1;
    y0 = min(max(y0, 0), Hs-1); y1 = min(max(y1, 0), Hs-1);
    long plane = (long)Hs * Ws;
    int xl = t & 63, c4 = t >> 6;
    for (int xp = 0; xp < 4; ++xp) {
      int x = xp*64 + xl;
      if (x < 224) {
        float fx  = (x + 0.5f) * invS - 0.5f;
        float x0f = floorf(fx);
        float wx1 = fx - x0f, wx0 = 1.f - wx1;
        int x0 = (int)x0f, x1 = (int)x0f + 1;
        x0 = min(max(x0, 0), Ws-1); x1 = min(max(x1, 0), Ws-1);
        int o00 = y0*Ws + x0, o01 = y0*Ws + x1;
        int o10 = y1*Ws + x0, o11 = y1*Ws + x1;
#pragma unroll
        for (int pp = 0; pp < 8; ++pp) {
          int pr = c4*8 + pp;
          const float* base0 = src + ((long)(b*256 + cc0 + 2*pr)) * plane;
          const float* base1 = base0 + plane;
          float va = wy0*(wx0*base0[o00] + wx1*base0[o01])
                   + wy1*(wx0*base0[o10] + wx1*base0[o11]);
          float vb = wy0*(wx0*base1[o00] + wx1*base1[o01])
                   + wy1*(wx0*base1[o10] + wx1*base1[o11]);
          tile[pr*225 + x] = pk2(va, vb);
        }
      }
    }
  }
  __syncthreads();
  // phase 2: lane q covers pairs q*4..q*4+3 (channels q*8..q*8+7) of row x
  int q = t & 7, xg = t >> 3;
  float4 u0, u1;
  if (do_ub) {
    u0 = *(const float4*)(us + q*8);
    u1 = *(const float4*)(us + q*8 + 4);
  }
  for (int xo = 0; xo < 7; ++xo) {
    int x = xo*32 + xg;
    unsigned p0 = tile[(q*4+0)*225 + x];
    unsigned p1 = tile[(q*4+1)*225 + x];
    unsigned p2 = tile[(q*4+2)*225 + x];
    unsigned p3 = tile[(q*4+3)*225 + x];
    int px = x / 14, j = x % 14;
    int m = i*14 + j;
    long nm = (long)(b*256 + py*16 + px) * 196 + m;
    uint4 w; w.x = p0; w.y = p1; w.z = p2; w.w = p3;
    *reinterpret_cast<uint4*>(dst + nm*256 + cc0 + q*8) = w;
    if (do_ub) {
      union { unsigned u; f16 h[2]; } c0, c1, c2, c3;
      c0.u = p0; c1.u = p1; c2.u = p2; c3.u = p3;
      float part = u0.x*(float)c0.h[0] + u0.y*(float)c0.h[1]
                 + u0.z*(float)c1.h[0] + u0.w*(float)c1.h[1]
                 + u1.x*(float)c2.h[0] + u1.y*(float)c2.h[1]
                 + u1.z*(float)c3.h[0] + u1.w*(float)c3.h[1];
      part += __shfl_xor(part, 1);
      part += __shfl_xor(part, 2);
      part += __shfl_xor(part, 4);
      if (q == 0) ub4[(long)(bx & 3) * NLROWS + nm] = part;
    }
  }
}

// ---------------- k2: [Kt | V] = SPT * [G; Wv]^T. BM=64 nm-rows, BN=512, col-split waves ----------
// KtT[nm][256] (bt-layout for k3), V transposed via LDS -> VT2[n][c][224] (bt-layout for PV)
__global__ __launch_bounds__(256) void k2_kv(
    const f16* __restrict__ SPT, const f16* __restrict__ G16,
    const f16* __restrict__ Wv16, f16* __restrict__ KtT, f16* __restrict__ VT2) {
  __shared__ __align__(16) char ldsA[64 * 80];    // [row][32 f16 -> 80B padded]
  __shared__ __align__(16) char ldsB[512 * 80];   // reused as [64][258] f16 for V transpose
  int tid = threadIdx.x;
  int lane = tid & 63, wv = tid >> 6;
  long nm0 = (long)blockIdx.x * 64;
  f32x4 zero = {0.f, 0.f, 0.f, 0.f};
  f32x4 acc[4][8];
#pragma unroll
  for (int a = 0; a < 4; ++a)
#pragma unroll
    for (int bb = 0; bb < 8; ++bb) acc[a][bb] = zero;
  int col0 = wv * 128;
  int r15 = lane & 15, quad = lane >> 4;
  for (int k0 = 0; k0 < 256; k0 += 32) {
    __syncthreads();
#pragma unroll
    for (int call = 0; call < 2; ++call) {       // A: 320 slots
      int slot = call*256 + tid;
      if (slot < 320) {
        int row = slot / 5, part = slot % 5;
        int pp_ = part < 4 ? part : 0;           // slot 5 = pad, dup row start
        g2l16(SPT + ((nm0 + row)*256 + k0 + pp_*8), ldsA + slot*16);
      }
    }
#pragma unroll
    for (int call = 0; call < 10; ++call) {      // B: 2560 slots
      int slot = call*256 + tid;
      int row = slot / 5, part = slot % 5;
      int pp_ = part < 4 ? part : 0;
      const f16* g = (row < 256) ? (G16 + (row*256 + k0 + pp_*8))
                                 : (Wv16 + ((row - 256)*256 + k0 + pp_*8));
      g2l16(g, ldsB + slot*16);
    }
    __syncthreads();
    f16x8 af[4];
#pragma unroll
    for (int rt = 0; rt < 4; ++rt)
      af[rt] = *(const f16x8*)(ldsA + (rt*16 + r15)*80 + quad*16);
#pragma unroll
    for (int tc = 0; tc < 8; ++tc) {
      f16x8 bf = *(const f16x8*)(ldsB + (col0 + tc*16 + r15)*80 + quad*16);
#pragma unroll
      for (int rt = 0; rt < 4; ++rt)
        acc[rt][tc] = __builtin_amdgcn_mfma_f32_16x16x32_f16(af[rt], bf, acc[rt][tc], 0, 0, 0);
    }
  }
  __syncthreads();                // last MFMA ldsB reads done before reuse
  f16* ldsV = (f16*)ldsB;        // [64][258] (+2 pad -> bank-conflict-free transpose)
  if (wv >= 2) {                 // waves 2,3 hold V columns: stage to LDS
#pragma unroll
    for (int rt = 0; rt < 4; ++rt)
#pragma unroll
      for (int tc = 0; tc < 8; ++tc) {
        int o = col0 - 256 + tc*16 + r15;
#pragma unroll
        for (int reg = 0; reg < 4; ++reg) {
          int row = rt*16 + quad*4 + reg;
          ldsV[row*258 + o] = (f16)acc[rt][tc][reg];
        }
      }
  } else {                       // waves 0,1: K-tilde, already coalesced
#pragma unroll
    for (int rt = 0; rt < 4; ++rt)
#pragma unroll
      for (int tc = 0; tc < 8; ++tc) {
        int colc = col0 + tc*16 + r15;
#pragma unroll
        for (int reg = 0; reg < 4; ++reg) {
          long row = nm0 + rt*16 + quad*4 + reg;
          KtT[row*256 + colc] = (f16)acc[rt][tc][reg];
        }
      }
  }
  __syncthreads();
  {                              // transpose-write V: contiguous along m
    int row = tid & 63;
    long nm = nm0 + row;
    int n = (int)(nm / 196), m = (int)(nm % 196);
    long vbase = ((long)n * 256) * 224 + m;
    int o0 = (tid >> 6) * 64;
    for (int it = 0; it < 64; ++it) {
      int o = o0 + it;
      VT2[vbase + (long)o * 224] = ldsV[row*258 + o];
    }
  }
}

// ---------------- k3: fused S = XT.Kt^T (+ub) -> softmax -> P(LDS) -> O = P.V^T -----------
// LDS map: [0,29696) = P (64 rows x 464B pitch), overlaid on S-phase tiles
//          (A@0: 64x80B, B@5120: 208x80B); [29696,50176) = V chunk (256 x 80B).
// 50.2KB + ubs -> 3 blocks/CU. V chunk 0 prefetched async under the softmax.
__global__ __launch_bounds__(256) void k3_sv(
    const f16* __restrict__ XT, const f16* __restrict__ KtT,
    const float* __restrict__ ub, const f16* __restrict__ VT2,
    f16* __restrict__ Obuf, int mode) {
  __shared__ __align__(16) char lds[50176];
  __shared__ float ubs[208];
  char* ldsA = lds;
  char* ldsB = lds + 5120;
  char* ldsV = lds + 29696;
  int tid = threadIdx.x;
  int lane = tid & 63, wv = tid >> 6;
  int bx = blockIdx.x;
  // XCD swizzle: 4 blocks sharing KtT/VT2[n] slice land 8 apart -> same XCD, adjacent in time
  int n  = ((bx >> 5) << 3) | (bx & 7);
  int l0 = ((bx >> 3) & 3) * 64;
  long base = (long)n * 196;
  for (int s = tid; s < 208; s += 256) {
    float v = 0.f;
    if (s < 196) {
      long o = base + s;
      v = ub[o] + ub[NLROWS + o] + ub[2*NLROWS + o] + ub[3*NLROWS + o];
    }
    ubs[s] = v;
  }
  f32x4 zero = {0.f, 0.f, 0.f, 0.f};
  f32x4 acc[13];
#pragma unroll
  for (int t = 0; t < 13; ++t) acc[t] = zero;
  int r15 = lane & 15, quad = lane >> 4;
  long vrow = ((long)(n*256)) * 224;               // VT2 n-slice base

  for (int k0 = 0; k0 < 256; k0 += 32) {
    __syncthreads();
#pragma unroll
    for (int call = 0; call < 2; ++call) {        // A: 320 slots (5 per row)
      int slot = call*256 + tid;
      if (slot < 320) {
        int row = slot / 5, part = slot % 5;
        int pp_ = part < 4 ? part : 0;
        int l = l0 + row; l = l > 195 ? 195 : l;  // clamp ghost rows
        g2l16(XT + ((base + l)*256 + k0 + pp_*8), ldsA + slot*16);
      }
    }
#pragma unroll
    for (int call = 0; call < 5; ++call) {        // B: 1040 slots
      int slot = call*256 + tid;
      if (slot < 1040) {
        int row = slot / 5, part = slot % 5;
        int pp_ = part < 8 ? (part < 4 ? part : 0) : 0;
        int m = row > 195 ? 195 : row;
        g2l16(KtT + ((base + m)*256 + k0 + pp_*8), ldsB + slot*16);
      }
    }
    __syncthreads();
    f16x8 af = *(const f16x8*)(ldsA + (wv*16 + r15)*80 + quad*16);
#pragma unroll
    for (int t = 0; t < 13; ++t) {
      f16x8 bf = *(const f16x8*)(ldsB + (t*16 + r15)*80 + quad*16);
      acc[t] = __builtin_amdgcn_mfma_f32_16x16x32_f16(af, bf, acc[t], 0, 0, 0);
    }
  }

  // prefetch V chunk 0 (region untouched by S-phase); latency hides under softmax
#pragma unroll
  for (int call = 0; call < 5; ++call) {
    int slot = call*256 + tid;
    int row = slot / 5, part = slot % 5;
    int pp_ = part < 4 ? part : 0;
    g2l16(VT2 + (vrow + (long)row*224 + pp_*8), ldsV + slot*16);
  }

  // softmax over m (cols). C-layout: col = lane&15 + 16*t, row = quad*4+reg (+16*wv +l0)
  float mx[4] = {-1e30f, -1e30f, -1e30f, -1e30f};
#pragma unroll
  for (int t = 0; t < 13; ++t) {
    int colb = t*16 + r15;
    float ubv = ubs[colb];
    bool valid = colb < 196;
#pragma unroll
    for (int reg = 0; reg < 4; ++reg) {
      float v = acc[t][reg] + ubv;
      acc[t][reg] = v;
      if (valid) mx[reg] = fmaxf(mx[reg], v);
    }
  }
#pragma unroll
  for (int reg = 0; reg < 4; ++reg) {
    float m = mx[reg];
    m = fmaxf(m, __shfl_xor(m, 1));
    m = fmaxf(m, __shfl_xor(m, 2));
    m = fmaxf(m, __shfl_xor(m, 4));
    m = fmaxf(m, __shfl_xor(m, 8));
    mx[reg] = m;
  }
  float sum[4] = {0.f, 0.f, 0.f, 0.f};
#pragma unroll
  for (int t = 0; t < 13; ++t) {
    int colb = t*16 + r15;
    bool valid = colb < 196;
#pragma unroll
    for (int reg = 0; reg < 4; ++reg) {
      float p = valid ? __expf(acc[t][reg] - mx[reg]) : 0.f;
      acc[t][reg] = p;
      sum[reg] += p;
    }
  }
#pragma unroll
  for (int reg = 0; reg < 4; ++reg) {
    float s = sum[reg];
    s += __shfl_xor(s, 1);
    s += __shfl_xor(s, 2);
    s += __shfl_xor(s, 4);
    s += __shfl_xor(s, 8);
    sum[reg] = 1.0f / s;
  }

  __syncthreads();   // all S-phase LDS reads done -> safe to overlay P on A/B tiles
  // write P -> LDS, row pitch 464B (29 x 16B: rows stride 20 words mod 32, conflict-benign)
#pragma unroll
  for (int reg = 0; reg < 4; ++reg) {
    int row = wv*16 + quad*4 + reg;
    float sc = sum[reg];
#pragma unroll
    for (int t = 0; t < 13; ++t)
      *(f16*)(lds + row*464 + (t*16 + r15)*2) = (f16)(acc[t][reg] * sc);
  }
  {  // zero pad m in [208,224)
    int row = tid >> 2, mq = tid & 3;
    *(long*)(lds + row*464 + 416 + mq*8) = 0;
  }

  // PV phase: O[l][c] += sum_m P[l][m] V[c][m]; A from LDS-P, B = V chunk staged per m-step
  f32x4 oacc[16];
#pragma unroll
  for (int t = 0; t < 16; ++t) oacc[t] = zero;
  for (int it = 0; it < 7; ++it) {
    if (it > 0) {
      __syncthreads();                            // prev chunk's MFMA reads done
#pragma unroll
      for (int call = 0; call < 5; ++call) {      // V: 1280 slots
        int slot = call*256 + tid;
        int row = slot / 5, part = slot % 5;
        int pp_ = part < 4 ? part : 0;
        g2l16(VT2 + (vrow + (long)row*224 + it*32 + pp_*8), ldsV + slot*16);
      }
    }
    __syncthreads();                              // stage drained; it=0: P visible too
    f16x8 af = *(const f16x8*)(lds + (wv*16 + r15)*464 + it*64 + quad*16);
#pragma unroll
    for (int t = 0; t < 16; ++t) {
      f16x8 bf = *(const f16x8*)(ldsV + (t*16 + r15)*80 + quad*16);
      oacc[t] = __builtin_amdgcn_mfma_f32_16x16x32_f16(af, bf, oacc[t], 0, 0, 0);
    }
  }

#pragma unroll
  for (int reg = 0; reg < 4; ++reg) {
    int l = l0 + wv*16 + quad*4 + reg;
    if (l < 196) {
      long orow = (base + l) * 256;
#pragma unroll
      for (int t = 0; t < 16; ++t) {
        int c = t*16 + r15;
        float v = oacc[t][reg];
        if (mode == 0) Obuf[orow + c] = (f16)v;
        else           Obuf[orow + c] = (f16)(v + (float)Obuf[orow + c]);
      }
    }
  }
}

// ---------------- k5: unpatchify Obuf[n][l][c] -> out[b][c][yy][xx] + 2*bv -------------------
__global__ __launch_bounds__(256) void k5_unpatch(
    const f16* __restrict__ Obuf, const float* __restrict__ bv,
    float* __restrict__ out) {
  __shared__ float lds[64 * 225];   // [c_local][xx], stride 225 -> conflict-free both sides
  int bx = blockIdx.x;
  int cc = (bx & 3) * 64;  bx >>= 2;
  int i  = bx % 14; bx /= 14;
  int py = bx & 15; int b = bx >> 4;
  int t = threadIdx.x;
  int cl = t & 63, pg = t >> 6;
  for (int it = 0; it < 56; ++it) {
    int pr = it*4 + pg;            // (px,j) pair index, 0..223
    int px = pr / 14, j = pr % 14;
    int n = b*256 + py*16 + px;
    float v = (float)Obuf[((long)n*196 + i*14 + j)*256 + cc + cl];
    lds[cl*225 + px*14 + j] = v;
  }
  __syncthreads();
  int yy = py*14 + i;
  for (int c = 0; c < 64; ++c) {
    float bb = 2.0f * bv[cc + c];
    if (t < 224)
      out[(((long)(b*256 + cc + c))*224 + yy)*224 + t] = lds[c*225 + t] + bb;
  }
}

extern "C" void kernel_launch(void* const* d_in, const int* in_sizes, int n_in,
                              void* d_out, int out_size, void* d_ws, size_t ws_size,
                              hipStream_t stream) {
  (void)in_sizes; (void)n_in; (void)out_size; (void)ws_size;
  const float* x     = (const float*)d_in[0];
  const float* skip0 = (const float*)d_in[1];
  const float* skip1 = (const float*)d_in[2];
  const float* Wq    = (const float*)d_in[3];
  const float* bq    = (const float*)d_in[4];
  const float* Wk    = (const float*)d_in[5];
  // d_in[6] = bk: algebraically drops out of softmax (row-constant)
  const float* Wv    = (const float*)d_in[7];
  const float* bv    = (const float*)d_in[8];
  float* out = (float*)d_out;

  char* ws = (char*)d_ws;
  size_t off = 0;
  auto alloc = [&](size_t bytes) {
    char* p = ws + off;
    off += (bytes + 255) & ~(size_t)255;
    return p;
  };
  f16*   XT   = (f16*)  alloc((size_t)NLROWS * 256 * 2);   // x packed, f16 [nl][c]
  f16*   SPT  = (f16*)  alloc((size_t)NLROWS * 256 * 2);   // skip packed
  f16*   KtT  = (f16*)  alloc((size_t)NLROWS * 256 * 2);   // Ktilde [nm][c]
  f16*   VT2  = (f16*)  alloc((size_t)NPATCH * 256 * 224 * 2); // V [n][c][m(224)]
  f16*   Obuf = (f16*)  alloc((size_t)NLROWS * 256 * 2);   // O accum f16 [n][l][c]
  float* ub   = (float*)alloc((size_t)NLROWS * 4 * 4);     // 4 chunk-partials [4][nm]
  f16*   G16  = (f16*)  alloc(256 * 256 * 2);
  f16*   Wv16 = (f16*)  alloc(256 * 256 * 2);
  float* u32  = (float*)alloc(256 * 4);

  k0_prep<<<258, 256, 0, stream>>>(Wq, Wk, Wv, bq, G16, Wv16, u32);
  k1_pack<<<3584, 256, 0, stream>>>(x, 224, 224, 1.0f, XT, nullptr, u32, 0);

  const float* skips[2] = {skip0, skip1};
  int   hs[2]   = {112, 56};
  float invs[2] = {0.5f, 0.25f};
  for (int s = 0; s < 2; ++s) {
    k1_pack<<<3584, 256, 0, stream>>>(skips[s], hs[s], hs[s], invs[s], SPT, ub, u32, 1);
    k2_kv<<<3136, 256, 0, stream>>>(SPT, G16, Wv16, KtT, VT2);
    k3_sv<<<4096, 256, 0, stream>>>(XT, KtT, ub, VT2, Obuf, s);
  }
  k5_unpatch<<<3584, 256, 0, stream>>>(Obuf, bv, out);
}